// Round 11
// baseline (217.587 us; speedup 1.0000x reference)
//
#include <hip/hip_runtime.h>

// EMD / Sinkhorn logits, linear-domain formulation.
// u = a ./ (K v), v = b ./ (K^T u), K = exp(-(1-sim)/eps), v0 = 1.
// logits[q,p] = (T/N1) * sum_ij u_i K_ij v_j sim_ij
// One wave64 per (q,p); lane (idx=l>>1, half=l&1) owns 16-wide row- and
// col-fragments of K.
// v3: (a) FMA chains are inline-asm v_fmac_f32 with "v" constraints so
//     Kr/Kc/uu/vv MUST live in arch VGPRs (round-9: VGPR_Count stayed 28
//     with setup-only pins -> compiler parked K in AGPRs, ~32 accvgpr
//     reads/iter). (b) No s_barrier: blockDim=64 is ONE wave; same-wave
//     DS ops are in-order, so write->read through LDS needs no barrier.

#define N_ITERS 100

static constexpr float EPSR     = 0.05f;
static constexpr float SCALE2   = 20.0f * 1.44269504088896340736f; // (1/eps)*log2(e)
static constexpr float LN2      = 0.69314718055994530942f;
static constexpr float T_OVER_N = 12.5f / 32.0f;

__device__ __forceinline__ float xor1_add(float x) {
    // lane 2i <-> 2i+1 exchange via DPP quad_perm [1,0,3,2] (VALU pipe)
    int yi = __builtin_amdgcn_mov_dpp(__builtin_bit_cast(int, x), 0xB1, 0xF, 0xF, true);
    return x + __builtin_bit_cast(float, yi);
}

// Hard-VGPR arithmetic: every operand must be in an arch VGPR at use.
#define FMUL(d, a, b) asm("v_mul_f32 %0, %1, %2"  : "=v"(d) : "v"(a), "v"(b))
#define FMAC(d, a, b) asm("v_fmac_f32 %0, %1, %2" : "+v"(d) : "v"(a), "v"(b))

// Opaque pin (setup only): forbids rematerialization of the exp2s.
#define PIN(x) asm volatile("" : "+v"(x))

__global__ __launch_bounds__(64)
void emd_sinkhorn(const float* __restrict__ sim,
                  const int* __restrict__ im_len,
                  const int* __restrict__ s_len,
                  float* __restrict__ out, int P) {
    __shared__ __align__(16) float uArr[32];
    __shared__ __align__(16) float vArr[32];

    const int bid  = blockIdx.x;
    const int q    = bid / P;
    const int p    = bid - q * P;
    const int l    = threadIdx.x;
    const int half = l & 1;     // which 16-wide chunk
    const int idx  = l >> 1;    // row for rowFrag / col for colFrag

    const float* tile = sim + (size_t)bid * 1024;

    // --- Row fragment: K[idx][16*half + k] (vectorized loads) ---
    float Kr[16], Kc[16];
    {
        const float4* rp = reinterpret_cast<const float4*>(tile + idx * 32 + half * 16);
        float4 r0 = rp[0], r1 = rp[1], r2 = rp[2], r3 = rp[3];
        float t[16] = {r0.x, r0.y, r0.z, r0.w, r1.x, r1.y, r1.z, r1.w,
                       r2.x, r2.y, r2.z, r2.w, r3.x, r3.y, r3.z, r3.w};
        #pragma unroll
        for (int k = 0; k < 16; ++k)
            Kr[k] = __builtin_amdgcn_exp2f((t[k] - 1.0f) * SCALE2);
    }
    // --- Col fragment: K[16*half + k][idx] (strided, setup-only, L1-hot) ---
    #pragma unroll
    for (int k = 0; k < 16; ++k) {
        float s_ = tile[(half * 16 + k) * 32 + idx];
        Kc[k] = __builtin_amdgcn_exp2f((s_ - 1.0f) * SCALE2);
    }
    #pragma unroll
    for (int k = 0; k < 16; ++k) { PIN(Kr[k]); PIN(Kc[k]); }

    // --- Marginals: a_i = ((i<len)+1e-5)/(len + 32e-5) (matches reference) ---
    const int lq = im_len[q];
    const int lp = s_len[p];
    const float a_i = (((idx < lq) ? 1.0f : 0.0f) + 1e-5f) / ((float)lq + 32.0f * 1e-5f);
    const float b_j = (((idx < lp) ? 1.0f : 0.0f) + 1e-5f) / ((float)lp + 32.0f * 1e-5f);

    const float4* up = reinterpret_cast<const float4*>(&uArr[half * 16]);
    const float4* vp = reinterpret_cast<const float4*>(&vArr[half * 16]);

    float4 vv0{1.f,1.f,1.f,1.f}, vv1{1.f,1.f,1.f,1.f},
           vv2{1.f,1.f,1.f,1.f}, vv3{1.f,1.f,1.f,1.f};
    float u = 0.0f;

    #pragma unroll 1
    for (int it = 0; it < N_ITERS; ++it) {
        // ---------- u = a ./ (K v) ----------
        float s0, s1, s2, s3;
        FMUL(s0, Kr[ 0], vv0.x); FMUL(s1, Kr[ 1], vv0.y); FMUL(s2, Kr[ 2], vv0.z); FMUL(s3, Kr[ 3], vv0.w);
        FMAC(s0, Kr[ 4], vv1.x); FMAC(s1, Kr[ 5], vv1.y); FMAC(s2, Kr[ 6], vv1.z); FMAC(s3, Kr[ 7], vv1.w);
        FMAC(s0, Kr[ 8], vv2.x); FMAC(s1, Kr[ 9], vv2.y); FMAC(s2, Kr[10], vv2.z); FMAC(s3, Kr[11], vv2.w);
        FMAC(s0, Kr[12], vv3.x); FMAC(s1, Kr[13], vv3.y); FMAC(s2, Kr[14], vv3.z); FMAC(s3, Kr[15], vv3.w);
        float st = (s0 + s1) + (s2 + s3);
        st = xor1_add(st);                        // full row dot across lane pair
        float un = a_i * __builtin_amdgcn_rcpf(st);
        uArr[idx] = un;                           // both lanes, same value/addr
        __builtin_amdgcn_wave_barrier();          // compile-time ordering only
        float4 uu0 = up[0], uu1 = up[1], uu2 = up[2], uu3 = up[3];

        // ---------- v = b ./ (K^T u) ----------
        float t0, t1, t2, t3;
        FMUL(t0, Kc[ 0], uu0.x); FMUL(t1, Kc[ 1], uu0.y); FMUL(t2, Kc[ 2], uu0.z); FMUL(t3, Kc[ 3], uu0.w);
        FMAC(t0, Kc[ 4], uu1.x); FMAC(t1, Kc[ 5], uu1.y); FMAC(t2, Kc[ 6], uu1.z); FMAC(t3, Kc[ 7], uu1.w);
        FMAC(t0, Kc[ 8], uu2.x); FMAC(t1, Kc[ 9], uu2.y); FMAC(t2, Kc[10], uu2.z); FMAC(t3, Kc[11], uu2.w);
        FMAC(t0, Kc[12], uu3.x); FMAC(t1, Kc[13], uu3.y); FMAC(t2, Kc[14], uu3.z); FMAC(t3, Kc[15], uu3.w);
        float tt = (t0 + t1) + (t2 + t3);
        tt = xor1_add(tt);
        float vj = b_j * __builtin_amdgcn_rcpf(tt);
        vArr[idx] = vj;                           // both lanes, same value/addr
        __builtin_amdgcn_wave_barrier();
        vv0 = vp[0]; vv1 = vp[1]; vv2 = vp[2]; vv3 = vp[3];

        u = un;
    }

    // ---------- logits: sim = 1 + eps*ln(K); flow = u K v ----------
    float vvf[16] = {vv0.x, vv0.y, vv0.z, vv0.w, vv1.x, vv1.y, vv1.z, vv1.w,
                     vv2.x, vv2.y, vv2.z, vv2.w, vv3.x, vv3.y, vv3.z, vv3.w};
    float acc0 = 0.f, acc1 = 0.f;
    #pragma unroll
    for (int k = 0; k < 16; k += 2) {
        float f0 = u * Kr[k] * vvf[k];
        float sm0 = __builtin_fmaf(__builtin_amdgcn_logf(Kr[k]), EPSR * LN2, 1.0f);
        acc0 = __builtin_fmaf(f0, sm0, acc0);
        float f1 = u * Kr[k + 1] * vvf[k + 1];
        float sm1 = __builtin_fmaf(__builtin_amdgcn_logf(Kr[k + 1]), EPSR * LN2, 1.0f);
        acc1 = __builtin_fmaf(f1, sm1, acc1);
    }
    float part = acc0 + acc1;
    #pragma unroll
    for (int m = 1; m <= 32; m <<= 1) part += __shfl_xor(part, m, 64);
    if (l == 0) out[bid] = part * T_OVER_N;
}

extern "C" void kernel_launch(void* const* d_in, const int* in_sizes, int n_in,
                              void* d_out, int out_size, void* d_ws, size_t ws_size,
                              hipStream_t stream) {
    const float* sim    = (const float*)d_in[0];
    // d_in[1] (im_set) and d_in[2] (s_seq) are unused by the reference.
    const int*   im_len = (const int*)d_in[3];
    const int*   s_len  = (const int*)d_in[4];
    float*       out    = (float*)d_out;

    const int Q = in_sizes[3];
    const int P = in_sizes[4];

    dim3 grid(Q * P), block(64);
    hipLaunchKernelGGL(emd_sinkhorn, grid, block, 0, stream, sim, im_len, s_len, out, P);
}